// Round 3
// baseline (150.641 us; speedup 1.0000x reference)
//
#include <hip/hip_runtime.h>
#include <hip/hip_bf16.h>

// Single-head causal self-attention, B=4 T=4096 C=1024 H=128, f32 in/out.
// prep_w: W -> Wt bf16 [384][1024] (n-major, Q prescaled by H^-0.5)
// proj:   x@W for all 3 W in one x pass; W frags direct from L2; V transposed
// attn:   flash causal, QBLK=128 (4 waves x 32 rows), kv-split chunk=512
// combine: merge <=8 partials per q-block
//
// ws map (bytes):
//   Wt    [0,        786432)
//   Qb    [786432,   +4MB)
//   Kb    [+4MB)
//   Vt    [+4MB)                      -> 13369344
//   Opart [13369344, 576*64KB)        -> 51118080
//   ml    [51118080, +589824)         -> 51707904

typedef unsigned short u16;
typedef __attribute__((ext_vector_type(8))) __bf16 bf16x8;
typedef __attribute__((ext_vector_type(8))) u16 u16x8;
typedef __attribute__((ext_vector_type(4))) u16 u16x4;
typedef __attribute__((ext_vector_type(4))) float f32x4;

#define T_DIM 4096
#define C_DIM 1024
#define H_DIM 128
#define EPB 144  // split entries per batch: sum_{qb<32} ceil((qb+1)/4)
#define WS_SPLIT_NEED 51707904ull

static __device__ __forceinline__ f32x4 mfma16x16(u16x8 a, u16x8 b, f32x4 c) {
  return __builtin_amdgcn_mfma_f32_16x16x32_bf16(
      __builtin_bit_cast(bf16x8, a), __builtin_bit_cast(bf16x8, b), c, 0, 0, 0);
}

static __device__ __forceinline__ u16 f2bf(float f) {
  __hip_bfloat16 h = __float2bfloat16(f);
  return __builtin_bit_cast(u16, h);
}

// ---------------------------------------------------------------- prep_w ----
// Wt[n384][k]: n384 = [0,128) K, [128,256) Q (prescaled), [256,384) V.
__global__ __launch_bounds__(256) void prep_w_kernel(
    const float* __restrict__ wk, const float* __restrict__ wq,
    const float* __restrict__ wv, u16* __restrict__ Wt) {
  int idx = blockIdx.x * 256 + threadIdx.x;  // 3*128*1024 exact
  int w = idx >> 17;
  int r = idx & 131071;
  int n = r >> 10;
  int k = r & 1023;
  const float* W = (w == 0) ? wk : (w == 1) ? wq : wv;
  float v = W[k * H_DIM + n];
  if (w == 1) v *= 0.08838834764831845f;  // fold 128^-0.5 into Wq
  Wt[idx] = f2bf(v);
}

// ------------------------------------------------------------------ proj ----
// 256 blocks x 64 rows. x staged in LDS (128 k-cols/iter); W frags loaded
// straight from L2 (Wt fully L2-resident). Wave w owns cols f*64+w*16+lq,
// f=0,1 -> K; 2,3 -> Q; 4,5 -> V (V transposed via LDS at the end).
__global__ __launch_bounds__(256) void proj_kernel(
    const float* __restrict__ x, const u16* __restrict__ Wt,
    u16* __restrict__ Qb, u16* __restrict__ Kb, u16* __restrict__ Vt) {
  __shared__ __attribute__((aligned(16))) u16 Xl[64 * 136];
  __shared__ __attribute__((aligned(16))) u16 Vs[128 * 72];
  const int m0 = blockIdx.x * 64;
  const int t = threadIdx.x;
  const int wave = t >> 6, lane = t & 63;
  const int g = lane >> 4, lq = lane & 15;

  f32x4 acc[4][6] = {};

  for (int k0 = 0; k0 < C_DIM; k0 += 128) {
    __syncthreads();
#pragma unroll
    for (int p = 0; p < 8; ++p) {  // stage x 64x128 f32 -> bf16
      int idx = p * 256 + t;
      int row = idx >> 5, c4 = (idx & 31) * 4;
      float4 v = *(const float4*)&x[(size_t)(m0 + row) * C_DIM + k0 + c4];
      u16x4 bv;
      bv.x = f2bf(v.x); bv.y = f2bf(v.y); bv.z = f2bf(v.z); bv.w = f2bf(v.w);
      *(u16x4*)&Xl[row * 136 + c4] = bv;
    }
    __syncthreads();
#pragma unroll
    for (int c = 0; c < 4; ++c) {
      u16x8 bfr[6];
#pragma unroll
      for (int f = 0; f < 6; ++f)
        bfr[f] = *(const u16x8*)&Wt[(size_t)(f * 64 + wave * 16 + lq) * C_DIM +
                                    k0 + c * 32 + g * 8];
      u16x8 a[4];
#pragma unroll
      for (int rf = 0; rf < 4; ++rf)
        a[rf] = *(const u16x8*)&Xl[(rf * 16 + lq) * 136 + c * 32 + g * 8];
#pragma unroll
      for (int rf = 0; rf < 4; ++rf)
#pragma unroll
        for (int f = 0; f < 6; ++f)
          acc[rf][f] = mfma16x16(a[rf], bfr[f], acc[rf][f]);
    }
  }

  // K, Q epilogue (row = m0 + rf*16 + g*4 + r, col = f*64 + wave*16 + lq)
#pragma unroll
  for (int f = 0; f < 2; ++f) {
    const int col = f * 64 + wave * 16 + lq;
#pragma unroll
    for (int rf = 0; rf < 4; ++rf)
#pragma unroll
      for (int r = 0; r < 4; ++r) {
        size_t row = (size_t)(m0 + rf * 16 + g * 4 + r);
        Kb[row * H_DIM + col] = f2bf(acc[rf][f][r]);
        Qb[row * H_DIM + col] = f2bf(acc[rf][2 + f][r]);
      }
  }
  // V: transpose via LDS -> Vt[b][h][t]
  __syncthreads();
#pragma unroll
  for (int f = 0; f < 2; ++f)
#pragma unroll
    for (int rf = 0; rf < 4; ++rf)
#pragma unroll
      for (int r = 0; r < 4; ++r)
        Vs[(f * 64 + wave * 16 + lq) * 72 + rf * 16 + g * 4 + r] =
            f2bf(acc[rf][4 + f][r]);
  __syncthreads();
  {
    const int b = m0 >> 12, t0 = m0 & 4095;
#pragma unroll
    for (int p = 0; p < 4; ++p) {
      int idx = p * 256 + t;
      int h = idx >> 3, mc = (idx & 7) * 8;
      *(u16x8*)&Vt[(size_t)b * (H_DIM * T_DIM) + (size_t)h * T_DIM + t0 + mc] =
          *(const u16x8*)&Vs[h * 72 + mc];
    }
  }
}

// ------------------------------------------------------------------ attn ----
// QBLK=128: 4 waves x 32 q-rows (2 row-frags). split: grid (EPB,4), chunk =
// 8 kv-tiles (512). Fully-masked diagonal tiles skipped per-wave.
__global__ __launch_bounds__(256) void attn_kernel(
    const u16* __restrict__ Qb, const u16* __restrict__ Kb,
    const u16* __restrict__ Vt, float* __restrict__ out,
    float* __restrict__ Opart, float* __restrict__ ml, int split) {
  __shared__ __attribute__((aligned(16))) u16 Kl[64 * 136];
  __shared__ __attribute__((aligned(16))) u16 Vl[128 * 72];
  __shared__ __attribute__((aligned(16))) u16 Pl[4][32 * 72];
  const int t = threadIdx.x;
  const int wave = t >> 6, lane = t & 63;
  const int g = lane >> 4, lq = lane & 15;

  int b, qb, kvb, kve, pid;
  if (split) {
    b = blockIdx.y;
    int e = (EPB - 1) - (int)blockIdx.x;  // heavy chunks dispatch first
    int a = 0;
#pragma unroll
    for (int c = 1; c < 8; ++c)
      if (e >= 2 * c * (c + 1)) a = c;
    int off = e - 2 * a * (a + 1);
    int npc = a + 1;
    int d = off / npc;
    qb = 4 * a + d;
    int ch = off - d * npc;
    kvb = ch * 512;
    pid = b * EPB + e;
    int kv_full = qb * 128 + 128;
    kve = (kvb + 512 < kv_full) ? kvb + 512 : kv_full;
  } else {
    b = blockIdx.x & 3;
    qb = 31 - ((int)blockIdx.x >> 2);
    kvb = 0;
    kve = qb * 128 + 128;
    pid = 0;
  }
  const int q0 = qb * 128;
  const int rowb = q0 + wave * 32;  // wave's first global q-row

  u16x8 qf[2][4];  // 32 q-rows x 128, A-frag layout (prescaled)
#pragma unroll
  for (int rf = 0; rf < 2; ++rf) {
    const u16* Qp = Qb + (size_t)(b * T_DIM + rowb + rf * 16 + lq) * H_DIM;
#pragma unroll
    for (int c = 0; c < 4; ++c) qf[rf][c] = *(const u16x8*)&Qp[c * 32 + g * 8];
  }

  f32x4 ao[2][8] = {};
  float m_run[2][4], l_run[2][4];
#pragma unroll
  for (int rf = 0; rf < 2; ++rf)
#pragma unroll
    for (int r = 0; r < 4; ++r) { m_run[rf][r] = -INFINITY; l_run[rf][r] = 0.f; }

  const int krow = t >> 4, kcol = (t & 15) * 8;
  const int vrow = t >> 3, vcol = (t & 7) * 8;
  const u16* Kg0 = Kb + (size_t)b * T_DIM * H_DIM;
  const u16* Vg0 = Vt + (size_t)b * H_DIM * T_DIM;

  for (int kv0 = kvb; kv0 < kve; kv0 += 64) {
    __syncthreads();
#pragma unroll
    for (int p = 0; p < 4; ++p) {  // K tile [64][128] -> [64][136]
      int r = p * 16 + krow;
      *(u16x8*)&Kl[r * 136 + kcol] =
          *(const u16x8*)&Kg0[(size_t)(kv0 + r) * H_DIM + kcol];
    }
#pragma unroll
    for (int p = 0; p < 4; ++p) {  // Vt tile [128][64] -> [128][72]
      int h = p * 32 + vrow;
      *(u16x8*)&Vl[h * 72 + vcol] =
          *(const u16x8*)&Vg0[(size_t)h * T_DIM + kv0 + vcol];
    }
    __syncthreads();

    if (kv0 > rowb + 31) continue;  // fully masked for this wave (uniform)

    // S = Q K^T (Q prescaled): K frags shared across both row-frags
    f32x4 s[2][4];
#pragma unroll
    for (int rf = 0; rf < 2; ++rf)
#pragma unroll
      for (int nf = 0; nf < 4; ++nf) s[rf][nf] = f32x4{0.f, 0.f, 0.f, 0.f};
#pragma unroll
    for (int nf = 0; nf < 4; ++nf)
#pragma unroll
      for (int c = 0; c < 4; ++c) {
        u16x8 kf = *(const u16x8*)&Kl[(nf * 16 + lq) * 136 + c * 32 + g * 8];
#pragma unroll
        for (int rf = 0; rf < 2; ++rf)
          s[rf][nf] = mfma16x16(qf[rf][c], kf, s[rf][nf]);
      }

    if (kv0 >= q0) {  // boundary region: elementwise causal mask
#pragma unroll
      for (int rf = 0; rf < 2; ++rf) {
        int row = rowb + rf * 16 + g * 4;
#pragma unroll
        for (int nf = 0; nf < 4; ++nf) {
          int col = kv0 + nf * 16 + lq;
#pragma unroll
          for (int r = 0; r < 4; ++r)
            if (col > row + r) s[rf][nf][r] = -INFINITY;
        }
      }
    }

    // online softmax; rows (rf,4g+r) live in 16-lane group g
    float mloc[2][4];
#pragma unroll
    for (int rf = 0; rf < 2; ++rf)
#pragma unroll
      for (int r = 0; r < 4; ++r)
        mloc[rf][r] = fmaxf(fmaxf(s[rf][0][r], s[rf][1][r]),
                            fmaxf(s[rf][2][r], s[rf][3][r]));
#pragma unroll
    for (int off = 1; off < 16; off <<= 1)
#pragma unroll
      for (int rf = 0; rf < 2; ++rf)
#pragma unroll
        for (int r = 0; r < 4; ++r)
          mloc[rf][r] = fmaxf(mloc[rf][r], __shfl_xor(mloc[rf][r], off));

    float al[2][4], ps[2][4];
#pragma unroll
    for (int rf = 0; rf < 2; ++rf)
#pragma unroll
      for (int r = 0; r < 4; ++r) {
        float mn = fmaxf(m_run[rf][r], mloc[rf][r]);
        al[rf][r] = __expf(m_run[rf][r] - mn);
        m_run[rf][r] = mn;
        ps[rf][r] = 0.f;
      }
#pragma unroll
    for (int rf = 0; rf < 2; ++rf)
#pragma unroll
      for (int nf = 0; nf < 4; ++nf)
#pragma unroll
        for (int r = 0; r < 4; ++r) {
          float p = __expf(s[rf][nf][r] - m_run[rf][r]);
          s[rf][nf][r] = p;
          ps[rf][r] += p;
        }
#pragma unroll
    for (int off = 1; off < 16; off <<= 1)
#pragma unroll
      for (int rf = 0; rf < 2; ++rf)
#pragma unroll
        for (int r = 0; r < 4; ++r) ps[rf][r] += __shfl_xor(ps[rf][r], off);
#pragma unroll
    for (int rf = 0; rf < 2; ++rf)
#pragma unroll
      for (int r = 0; r < 4; ++r)
        l_run[rf][r] = l_run[rf][r] * al[rf][r] + ps[rf][r];
#pragma unroll
    for (int rf = 0; rf < 2; ++rf)
#pragma unroll
      for (int h8 = 0; h8 < 8; ++h8)
#pragma unroll
        for (int r = 0; r < 4; ++r) ao[rf][h8][r] *= al[rf][r];

    // P (D-layout) -> per-wave LDS -> A-layout frags for PV
#pragma unroll
    for (int rf = 0; rf < 2; ++rf)
#pragma unroll
      for (int nf = 0; nf < 4; ++nf)
#pragma unroll
        for (int r = 0; r < 4; ++r)
          Pl[wave][(rf * 16 + g * 4 + r) * 72 + nf * 16 + lq] =
              f2bf(s[rf][nf][r]);

    u16x8 pf[2][2];
#pragma unroll
    for (int rf = 0; rf < 2; ++rf)
#pragma unroll
      for (int kk = 0; kk < 2; ++kk)
        pf[rf][kk] =
            *(const u16x8*)&Pl[wave][(rf * 16 + lq) * 72 + kk * 32 + g * 8];
#pragma unroll
    for (int h8 = 0; h8 < 8; ++h8)
#pragma unroll
      for (int kk = 0; kk < 2; ++kk) {
        u16x8 vf = *(const u16x8*)&Vl[(h8 * 16 + lq) * 72 + kk * 32 + g * 8];
#pragma unroll
        for (int rf = 0; rf < 2; ++rf)
          ao[rf][h8] = mfma16x16(pf[rf][kk], vf, ao[rf][h8]);
      }
  }

  if (!split) {
    float inv[2][4];
#pragma unroll
    for (int rf = 0; rf < 2; ++rf)
#pragma unroll
      for (int r = 0; r < 4; ++r) inv[rf][r] = 1.f / l_run[rf][r];
#pragma unroll
    for (int rf = 0; rf < 2; ++rf) {
      float* Og = out + (size_t)(b * T_DIM + rowb + rf * 16 + g * 4) * H_DIM;
#pragma unroll
      for (int h8 = 0; h8 < 8; ++h8)
#pragma unroll
        for (int r = 0; r < 4; ++r)
          Og[(size_t)r * H_DIM + h8 * 16 + lq] = ao[rf][h8][r] * inv[rf][r];
    }
  } else {
#pragma unroll
    for (int rf = 0; rf < 2; ++rf) {
      float* Op = Opart + (size_t)pid * 16384 +
                  (size_t)(wave * 32 + rf * 16 + g * 4) * H_DIM;
#pragma unroll
      for (int h8 = 0; h8 < 8; ++h8)
#pragma unroll
        for (int r = 0; r < 4; ++r)
          Op[(size_t)r * H_DIM + h8 * 16 + lq] = ao[rf][h8][r];
    }
    if (lq == 0) {
      float* mlp = ml + (size_t)pid * 256;
#pragma unroll
      for (int rf = 0; rf < 2; ++rf)
#pragma unroll
        for (int r = 0; r < 4; ++r) {
          int row = wave * 32 + rf * 16 + g * 4 + r;
          mlp[row] = m_run[rf][r];
          mlp[128 + row] = l_run[rf][r];
        }
    }
  }
}

// --------------------------------------------------------------- combine ----
// grid (32, 4): merge the <=8 kv-split partials of one 128-row q-block.
__global__ __launch_bounds__(256) void combine_kernel(
    const float* __restrict__ Opart, const float* __restrict__ ml,
    float* __restrict__ out) {
  const int qb = blockIdx.x, b = blockIdx.y;
  const int t = threadIdx.x;
  const int row = t >> 1;
  const int colb = (t & 1) * 64;
  const int a = qb >> 2, d = qb & 3;
  const int n = a + 1;
  const int base = 2 * a * (a + 1) + d * (a + 1);
  const int pid0 = b * EPB + base;

  float mv[8];
#pragma unroll
  for (int i = 0; i < 8; ++i)
    mv[i] = (i < n) ? ml[(size_t)(pid0 + i) * 256 + row] : -INFINITY;
  float M = mv[0];
#pragma unroll
  for (int i = 1; i < 8; ++i) M = fmaxf(M, mv[i]);

  float L = 0.f;
  f32x4 o[16] = {};
#pragma unroll
  for (int i = 0; i < 8; ++i)
    if (i < n) {
      float sc = __expf(mv[i] - M);
      L += sc * ml[(size_t)(pid0 + i) * 256 + 128 + row];
      const f32x4* Op = (const f32x4*)(Opart + (size_t)(pid0 + i) * 16384 +
                                       (size_t)row * H_DIM + colb);
#pragma unroll
      for (int p = 0; p < 16; ++p) o[p] += sc * Op[p];
    }
  float inv = 1.f / L;
  f32x4* Og =
      (f32x4*)(out + ((size_t)b * T_DIM + qb * 128 + row) * H_DIM + colb);
#pragma unroll
  for (int p = 0; p < 16; ++p) Og[p] = o[p] * inv;
}

// ---------------------------------------------------------------- launch ----
extern "C" void kernel_launch(void* const* d_in, const int* in_sizes, int n_in,
                              void* d_out, int out_size, void* d_ws,
                              size_t ws_size, hipStream_t stream) {
  const float* x = (const float*)d_in[0];
  const float* wk = (const float*)d_in[1];
  const float* wq = (const float*)d_in[2];
  const float* wv = (const float*)d_in[3];
  float* out = (float*)d_out;
  char* ws = (char*)d_ws;

  u16* Wt = (u16*)ws;
  u16* Qb = (u16*)(ws + 786432);
  u16* Kb = (u16*)(ws + 786432 + 4194304);
  u16* Vt = (u16*)(ws + 786432 + 8388608);
  float* Opart = (float*)(ws + 13369344);
  float* ml = (float*)(ws + 51118080);

  const int split = (ws_size >= WS_SPLIT_NEED) ? 1 : 0;

  prep_w_kernel<<<1536, 256, 0, stream>>>(wk, wq, wv, Wt);
  proj_kernel<<<256, 256, 0, stream>>>(x, Wt, Qb, Kb, Vt);
  if (split) {
    attn_kernel<<<dim3(EPB, 4), 256, 0, stream>>>(Qb, Kb, Vt, out, Opart, ml, 1);
    combine_kernel<<<dim3(32, 4), 256, 0, stream>>>(Opart, ml, out);
  } else {
    attn_kernel<<<128, 256, 0, stream>>>(Qb, Kb, Vt, out, Opart, ml, 0);
  }
}